// Round 19
// baseline (839.821 us; speedup 1.0000x reference)
//
#include <hip/hip_runtime.h>
#include <hip/hip_bf16.h>
#include <math.h>

// Problem constants
#define BB  32
#define CC  256
#define NZ  169     // 13*13
#define NX  625     // 25*25

typedef _Float16 f16x4 __attribute__((ext_vector_type(4)));
typedef _Float16 f16x8 __attribute__((ext_vector_type(8)));
typedef float    f32x4 __attribute__((ext_vector_type(4)));

__device__ __forceinline__ float geluf(float x) {
  return 0.5f * x * (1.0f + erff(x * 0.7071067811865476f));
}

// ======================= fp32 vector GEMM (mask-path ops) =======================
struct GP {
  const float* A;  const float* B;
  const float* bias; const float* gamma; const float* beta; const float* mean; const float* var;
  const float* resid;
  float* out;
  int M, N, K;
  long aB, bB, outB;
};

#define TM 64
#define TN 64
#define TK 16

// AG: 0 = A[m,k] row-major ; 1 = A[m,k] = Abase[k*M + m]
// EPI:0 = none ; 2 = +bias,BN,GELU ; 3 = +resid
template<int AG, int EPI>
__global__ __launch_bounds__(256) void gemm_k(GP p) {
  const int b  = blockIdx.z;
  const int m0 = blockIdx.y * TM;
  const int n0 = blockIdx.x * TN;
  const float* Ab = p.A + (size_t)b * p.aB;
  const float* Bb = p.B + (size_t)b * p.bB;
  __shared__ __align__(16) float As[TK][TM + 4];
  __shared__ __align__(16) float Bs[TK][TN + 4];
  const int tid = threadIdx.x;
  const int tx = tid & 15, ty = tid >> 4;
  float acc[4][4] = {{0.f}};
  const int nK = (p.K + TK - 1) / TK;
  for (int kb = 0; kb < nK; ++kb) {
    const int k0 = kb * TK;
    if (AG == 0) {
      #pragma unroll
      for (int i = 0; i < 4; ++i) {
        int e = tid * 4 + i;
        int am = e >> 4, ak = e & 15;
        int gm = m0 + am, gk = k0 + ak;
        float v = 0.f;
        if (gm < p.M && gk < p.K) v = Ab[(size_t)gm * p.K + gk];
        As[ak][am] = v;
      }
    } else {
      #pragma unroll
      for (int i = 0; i < 4; ++i) {
        int e = tid + 256 * i;
        int ak = e >> 6, am = e & 63;
        int gm = m0 + am, gk = k0 + ak;
        float v = 0.f;
        if (gm < p.M && gk < p.K) v = Ab[(size_t)gk * p.M + gm];
        As[ak][am] = v;
      }
    }
    #pragma unroll
    for (int i = 0; i < 4; ++i) {
      int e = tid + 256 * i;
      int bk = e >> 6, bn = e & 63;
      int gk = k0 + bk, gn = n0 + bn;
      float v = 0.f;
      if (gk < p.K && gn < p.N) v = Bb[(size_t)gk * p.N + gn];
      Bs[bk][bn] = v;
    }
    __syncthreads();
    #pragma unroll
    for (int kk = 0; kk < TK; ++kk) {
      float av[4], bv[4];
      #pragma unroll
      for (int i2 = 0; i2 < 4; ++i2) av[i2] = As[kk][ty * 4 + i2];
      #pragma unroll
      for (int j2 = 0; j2 < 4; ++j2) bv[j2] = Bs[kk][tx * 4 + j2];
      #pragma unroll
      for (int i2 = 0; i2 < 4; ++i2)
        #pragma unroll
        for (int j2 = 0; j2 < 4; ++j2)
          acc[i2][j2] = fmaf(av[i2], bv[j2], acc[i2][j2]);
    }
    __syncthreads();
  }
  #pragma unroll
  for (int i = 0; i < 4; ++i) {
    int gm = m0 + ty * 4 + i;
    if (gm >= p.M) continue;
    float bs = 0.f, sBN = 1.f, tBN = 0.f;
    if (EPI == 2) {
      bs = p.bias[gm];
      float sc = p.gamma[gm] / sqrtf(p.var[gm] + 1e-5f);
      sBN = sc; tBN = p.beta[gm] - p.mean[gm] * sc;
    }
    #pragma unroll
    for (int j = 0; j < 4; ++j) {
      int gn = n0 + tx * 4 + j;
      if (gn >= p.N) continue;
      float v = acc[i][j];
      if (EPI == 2) { v += bs; v = v * sBN + tBN; v = geluf(v); }
      if (EPI == 3) v += p.resid[(size_t)b * p.outB + (size_t)gm * p.N + gn];
      p.out[(size_t)b * p.outB + (size_t)gm * p.N + gn] = v;
    }
  }
}

// ========== fp32 GEMM, 64x128 tile, 4x8 micro (bias+BN+GELU epilogue) ==========
// Same per-element kk-order as gemm_k -> bit-identical results.
struct G8 {
  const float* A; const float* B;
  const float* bias; const float* gamma; const float* beta; const float* mean; const float* var;
  float* out;
  int M, N, K;
  long aB, bB, outB;
};

__global__ __launch_bounds__(256) void gemm8_k(G8 p) {
  const int b  = blockIdx.z;
  const int m0 = blockIdx.y * 64;
  const int n0 = blockIdx.x * 128;
  const float* Ab = p.A + (size_t)b * p.aB;
  const float* Bb = p.B + (size_t)b * p.bB;
  __shared__ __align__(16) float As[16][68];
  __shared__ __align__(16) float Bs[16][132];
  const int tid = threadIdx.x;
  const int tx = tid & 15, ty = tid >> 4;
  float acc[4][8] = {{0.f}};
  const int nK = (p.K + 15) / 16;
  for (int kb = 0; kb < nK; ++kb) {
    const int k0 = kb * 16;
    #pragma unroll
    for (int i = 0; i < 4; ++i) {
      int e = tid * 4 + i;
      int am = e >> 4, ak = e & 15;
      int gm = m0 + am, gk = k0 + ak;
      float v = 0.f;
      if (gm < p.M && gk < p.K) v = Ab[(size_t)gm * p.K + gk];
      As[ak][am] = v;
    }
    #pragma unroll
    for (int i = 0; i < 8; ++i) {
      int e = tid + 256 * i;
      int bk = e >> 7, bn = e & 127;
      int gk = k0 + bk, gn = n0 + bn;
      float v = 0.f;
      if (gk < p.K && gn < p.N) v = Bb[(size_t)gk * p.N + gn];
      Bs[bk][bn] = v;
    }
    __syncthreads();
    #pragma unroll
    for (int kk = 0; kk < 16; ++kk) {
      float av[4], bv[8];
      #pragma unroll
      for (int i2 = 0; i2 < 4; ++i2) av[i2] = As[kk][ty * 4 + i2];
      #pragma unroll
      for (int j2 = 0; j2 < 8; ++j2) bv[j2] = Bs[kk][tx * 8 + j2];
      #pragma unroll
      for (int i2 = 0; i2 < 4; ++i2)
        #pragma unroll
        for (int j2 = 0; j2 < 8; ++j2)
          acc[i2][j2] = fmaf(av[i2], bv[j2], acc[i2][j2]);
    }
    __syncthreads();
  }
  #pragma unroll
  for (int i = 0; i < 4; ++i) {
    int gm = m0 + ty * 4 + i;
    if (gm >= p.M) continue;
    float bs = p.bias[gm];
    float sc = p.gamma[gm] / sqrtf(p.var[gm] + 1e-5f);
    float tBN = p.beta[gm] - p.mean[gm] * sc;
    #pragma unroll
    for (int j = 0; j < 8; ++j) {
      int gn = n0 + tx * 8 + j;
      if (gn >= p.N) continue;
      float v = acc[i][j] + bs;
      v = geluf(v * sc + tBN);
      p.out[(size_t)b * p.outB + (size_t)gm * p.N + gn] = v;
    }
  }
}

// ===== dual fp32 GEMM, 64x128 tile, 4x8 micro, shared A (transposed gather) =====
// Same per-element kk-order as gemm2_k -> bit-identical results.
struct GP2 {
  const float* A; const float* B1; const float* B2;
  float* out1; float* out2;
  int M, N, K;                 // M=169, N=625, K=256
  long aB, bB, outB;
};

__global__ __launch_bounds__(256) void gemm28_k(GP2 p) {
  const int b  = blockIdx.z;
  const int m0 = blockIdx.y * 64;
  const int n0 = blockIdx.x * 128;
  const float* Ab  = p.A  + (size_t)b * p.aB;
  const float* B1b = p.B1 + (size_t)b * p.bB;
  const float* B2b = p.B2 + (size_t)b * p.bB;
  __shared__ __align__(16) float As [16][68];
  __shared__ __align__(16) float Bs1[16][132];
  __shared__ __align__(16) float Bs2[16][132];
  const int tid = threadIdx.x;
  const int tx = tid & 15, ty = tid >> 4;
  float acc1[4][8] = {{0.f}};
  float acc2[4][8] = {{0.f}};
  const int nK = (p.K + 15) / 16;
  for (int kb = 0; kb < nK; ++kb) {
    const int k0 = kb * 16;
    #pragma unroll
    for (int i = 0; i < 4; ++i) {
      int e = tid + 256 * i;
      int ak = e >> 6, am = e & 63;
      int gm = m0 + am, gk = k0 + ak;
      float v = 0.f;
      if (gm < p.M && gk < p.K) v = Ab[(size_t)gk * p.M + gm];
      As[ak][am] = v;
    }
    #pragma unroll
    for (int i = 0; i < 8; ++i) {
      int e = tid + 256 * i;
      int bk = e >> 7, bn = e & 127;
      int gk = k0 + bk, gn = n0 + bn;
      float v1 = 0.f, v2 = 0.f;
      if (gk < p.K && gn < p.N) {
        v1 = B1b[(size_t)gk * p.N + gn];
        v2 = B2b[(size_t)gk * p.N + gn];
      }
      Bs1[bk][bn] = v1;
      Bs2[bk][bn] = v2;
    }
    __syncthreads();
    #pragma unroll
    for (int kk = 0; kk < 16; ++kk) {
      float av[4], bv1[8], bv2[8];
      #pragma unroll
      for (int i2 = 0; i2 < 4; ++i2) av[i2] = As[kk][ty * 4 + i2];
      #pragma unroll
      for (int j2 = 0; j2 < 8; ++j2) { bv1[j2] = Bs1[kk][tx * 8 + j2]; bv2[j2] = Bs2[kk][tx * 8 + j2]; }
      #pragma unroll
      for (int i2 = 0; i2 < 4; ++i2)
        #pragma unroll
        for (int j2 = 0; j2 < 8; ++j2) {
          acc1[i2][j2] = fmaf(av[i2], bv1[j2], acc1[i2][j2]);
          acc2[i2][j2] = fmaf(av[i2], bv2[j2], acc2[i2][j2]);
        }
    }
    __syncthreads();
  }
  #pragma unroll
  for (int i = 0; i < 4; ++i) {
    int gm = m0 + ty * 4 + i;
    if (gm >= p.M) continue;
    #pragma unroll
    for (int j = 0; j < 8; ++j) {
      int gn = n0 + tx * 8 + j;
      if (gn >= p.N) continue;
      size_t o = (size_t)b * p.outB + (size_t)gm * p.N + gn;
      p.out1[o] = acc1[i][j];
      p.out2[o] = acc2[i][j];
    }
  }
}

// ======================= weight pre-transpose to f16 =======================
// W [M][C2][R] fp32  ->  Wt [R][M][C2p] f16 (zero-padded c >= C2)
__global__ __launch_bounds__(256) void wtr_k(const float* __restrict__ W,
                                             _Float16* __restrict__ Wt,
                                             int M, int C2, int C2p, int R) {
  size_t o = (size_t)blockIdx.x * 256 + threadIdx.x;
  size_t total = (size_t)R * M * C2p;
  if (o >= total) return;
  int c = (int)(o % C2p);
  int t = (int)(o / C2p);
  int m = t % M;
  int r = t / M;
  float v = 0.f;
  if (c < C2) v = W[((size_t)m * C2 + c) * R + r];
  Wt[o] = (_Float16)v;
}

// ======================= NCHW f32 (+opt add) -> NHWC f16 =======================
__global__ __launch_bounds__(256) void cvt_k(const float* __restrict__ A,
                                             const float* __restrict__ A2,
                                             _Float16* __restrict__ O,
                                             int C, int Cp, long total) {
  long o = (long)blockIdx.x * 256 + threadIdx.x;
  if (o >= total) return;
  int c = (int)(o % Cp);
  long t = o / Cp;
  int pp = (int)(t % NX);
  int b = (int)(t / NX);
  float v = 0.f;
  if (c < C) {
    size_t src = ((size_t)b * C + c) * NX + pp;
    v = A[src];
    if (A2) v += A2[src];
  }
  O[o] = (_Float16)v;
}

// ======================= f16 MFMA conv-as-GEMM (NHWC acts) =======================
// out[b][m][n] = epi( sum_{r,c} Wt[r][m][c] * U[b][pix(n,r)][c] )
// 64x64 tile, 4 waves (each 32x32), 16x16x32 MFMA, swizzled LDS (stride 64 f16,
// 16B-slot XOR), XCD-aware block swizzle. Grid MUST be dim3(10,4,32) = 1280.
// == R11 measured-best structure — DO NOT perturb (R13/R14/R15 all regressed) ==
struct MP {
  const _Float16* Wt;       // [R][256][C2p]
  const _Float16* U;        // [b][625][C2p]
  const float* mask;        // [b][625] (MASKED: applies to c>=256)
  const float* bias; const float* gamma; const float* beta; const float* mean; const float* var;
  float* out;               // f32 NCHW [b][256][625]   (OUT16 == 0)
  _Float16* out16;          // f16 NHWC [b][625][oC2p]  (OUT16 == 1)
  int R, Rw, C2p;
  long uB;                  // per-batch U stride
  int oC2p, oCoff;
};

// EPI: 1 = +bias ; 2 = +bias,BN,GELU
template<int EPI, int OUT16, int MASKED>
__global__ __launch_bounds__(256) void mgemm_k(MP p) {
  // ---- XCD-aware bijective swizzle: XCD x handles batches 4x..4x+3 ----
  const int L   = blockIdx.x + 10 * (blockIdx.y + 4 * blockIdx.z); // 0..1279
  const int xcd = L & 7;
  const int j   = L >> 3;                 // 0..159
  const int jb  = j / 40;                 // 0..3
  const int b   = (xcd << 2) + jb;
  const int t   = j - jb * 40;            // 0..39
  const int m0  = (t / 10) * 64;
  const int n0  = (t - (t / 10) * 10) * 64;

  __shared__ __align__(16) _Float16 As[64][64];   // 128B rows, swizzled 16B slots
  __shared__ __align__(16) _Float16 Bs[64][64];
  const int tid = threadIdx.x;
  const int w = tid >> 6, lane = tid & 63;
  const int wm = w & 1, wn = w >> 1;                // wave -> 32x32 sub-tile
  const int lm = lane & 15, q = lane >> 4;          // q = k-group 0..3
  const int sr = tid >> 2, sc4 = tid & 3;           // stage: row/pixel, 16-chan chunk
  const int scc = sc4 * 16;
  const int sr7 = sr & 7, sb = sc4 * 2;
  const int ng = n0 + sr;
  const bool nv = ng < NX;
  const int py = ng / 25, px = ng - (ng / 25) * 25;
  const _Float16* Ub = p.U + (size_t)b * p.uB;
  const float* mb = MASKED ? (p.mask + (size_t)b * NX) : nullptr;
  const int pad = p.Rw >> 1;

  f32x4 acc[2][2] = {};

  for (int r = 0; r < p.R; ++r) {
    const int kh = r / p.Rw, kw = r - (r / p.Rw) * p.Rw;
    const int iy = py + kh - pad, ix = px + kw - pad;
    const bool pv = nv && ((unsigned)iy < 25u) && ((unsigned)ix < 25u);
    const int pp = iy * 25 + ix;
    const _Float16* Up = pv ? (Ub + (size_t)pp * p.C2p) : nullptr;
    _Float16 mh = (_Float16)1.f;
    if (MASKED && pv) mh = (_Float16)mb[pp];
    const _Float16* Wr = p.Wt + ((size_t)r * 256 + m0) * p.C2p;
    for (int c0 = 0; c0 < p.C2p; c0 += 64) {
      // ---- A: 64x64 f16, 32 B/thread, coalesced ----
      const _Float16* Arow = Wr + (size_t)sr * p.C2p + c0 + scc;
      f16x8 a0 = *(const f16x8*)(Arow);
      f16x8 a1 = *(const f16x8*)(Arow + 8);
      // ---- B: 64x64 f16, 32 B/thread, coalesced ----
      f16x8 v0 = {}, v1 = {};
      if (pv) {
        const _Float16* Bp = Up + c0 + scc;
        v0 = *(const f16x8*)(Bp);
        v1 = *(const f16x8*)(Bp + 8);
        if (MASKED && (c0 + scc) >= 256) { v0 = v0 * mh; v1 = v1 * mh; }
      }
      *(f16x8*)&As[sr][((sb + 0) ^ sr7) << 3] = a0;
      *(f16x8*)&As[sr][((sb + 1) ^ sr7) << 3] = a1;
      *(f16x8*)&Bs[sr][((sb + 0) ^ sr7) << 3] = v0;
      *(f16x8*)&Bs[sr][((sb + 1) ^ sr7) << 3] = v1;
      __syncthreads();
      // ---- MFMA 16x16x32: wave (wm,wn) -> rows wm*32+ , cols wn*32+ ----
      #pragma unroll
      for (int ks = 0; ks < 2; ++ks) {
        const int so = (((ks << 2) + q) ^ (lm & 7)) << 3;  // rows ≡ lm (mod 8)
        f16x8 af[2], bf[2];
        #pragma unroll
        for (int fm = 0; fm < 2; ++fm)
          af[fm] = *(const f16x8*)&As[wm * 32 + fm * 16 + lm][so];
        #pragma unroll
        for (int fn = 0; fn < 2; ++fn)
          bf[fn] = *(const f16x8*)&Bs[wn * 32 + fn * 16 + lm][so];
        #pragma unroll
        for (int fm = 0; fm < 2; ++fm)
          #pragma unroll
          for (int fn = 0; fn < 2; ++fn)
            acc[fm][fn] = __builtin_amdgcn_mfma_f32_16x16x32_f16(
                af[fm], bf[fn], acc[fm][fn], 0, 0, 0);
      }
      __syncthreads();
    }
  }
  // ---- epilogue (C/D layout: col=lane&15, row=(lane>>4)*4+reg) ----
  #pragma unroll
  for (int fm = 0; fm < 2; ++fm) {
    const int rbase = m0 + wm * 32 + fm * 16 + q * 4;
    #pragma unroll
    for (int rr = 0; rr < 4; ++rr) {
      const int row = rbase + rr;
      float bs = p.bias[row];
      float sBN = 1.f, tBN = 0.f;
      if (EPI == 2) {
        float sc = p.gamma[row] / sqrtf(p.var[row] + 1e-5f);
        sBN = sc; tBN = p.beta[row] - p.mean[row] * sc;
      }
      #pragma unroll
      for (int fn = 0; fn < 2; ++fn) {
        const int col = n0 + wn * 32 + fn * 16 + lm;
        if (col < NX) {
          float v = acc[fm][fn][rr] + bs;
          if (EPI == 2) v = geluf(v * sBN + tBN);
          if (OUT16) {
            p.out16[((size_t)b * NX + col) * p.oC2p + p.oCoff + row] = (_Float16)v;
          } else {
            p.out[(size_t)b * (256 * NX) + (size_t)row * NX + col] = v;
          }
        }
      }
    }
  }
}

// ---------------- sparsemax (exact, Michelot projection) ----------------
// WAVE-per-row: lane holds NE strided elements; shfl-tree reductions only,
// zero barriers, zero LDS. 4 rows per 256-thread block.
template<int NE>
__global__ __launch_bounds__(256) void sparsemax_w(float* __restrict__ S,
                                                   int d, int nrows) {
  const int row = blockIdx.x * 4 + (threadIdx.x >> 6);
  const int lane = threadIdx.x & 63;
  if (row >= nrows) return;
  float* s = S + (size_t)row * d;
  float v[NE]; bool act[NE];
  #pragma unroll
  for (int j = 0; j < NE; ++j) {
    int idx = lane + 64 * j;
    bool ok = idx < d;
    act[j] = ok;
    v[j] = ok ? s[idx] : -1e30f;
  }
  // row max (wave shfl tree)
  float mx = v[0];
  #pragma unroll
  for (int j = 1; j < NE; ++j) mx = fmaxf(mx, v[j]);
  #pragma unroll
  for (int o = 32; o; o >>= 1) mx = fmaxf(mx, __shfl_down(mx, o));
  mx = __shfl(mx, 0);
  #pragma unroll
  for (int j = 0; j < NE; ++j) if (act[j]) v[j] -= mx;
  float tau = 0.f;
  for (int it = 0; it < 700; ++it) {
    float ls = 0.f, lc = 0.f;
    #pragma unroll
    for (int j = 0; j < NE; ++j) if (act[j]) { ls += v[j]; lc += 1.f; }
    #pragma unroll
    for (int o = 32; o; o >>= 1) { ls += __shfl_down(ls, o); lc += __shfl_down(lc, o); }
    ls = __shfl(ls, 0); lc = __shfl(lc, 0);
    tau = (ls - 1.f) / lc;
    bool ch = false;
    #pragma unroll
    for (int j = 0; j < NE; ++j)
      if (act[j] && v[j] <= tau) { act[j] = false; ch = true; }
    if (!__any(ch)) break;
  }
  #pragma unroll
  for (int j = 0; j < NE; ++j) {
    int idx = lane + 64 * j;
    if (idx < d) s[idx] = fmaxf(v[j] - tau, 0.f);
  }
}

// ------------- mask: any(si2>0) -> largest 8-CC -> fill holes -------------
__global__ __launch_bounds__(640) void cc_kernel(const float* __restrict__ si2,
                                                 float* __restrict__ mask) {
  const int b = blockIdx.x, tid = threadIdx.x;
  __shared__ int lab[625];
  __shared__ int counts[626];
  __shared__ int flag, best;
  const bool in = tid < 625;
  const int y = tid / 25, x = tid - (tid / 25) * 25;
  bool mv = false;
  if (in) {
    const float* base = si2 + (size_t)b * NZ * NX + tid;
    for (int n = 0; n < NZ; ++n) mv = mv || (base[(size_t)n * NX] > 0.f);
    lab[tid] = mv ? tid + 1 : 0;
  }
  __syncthreads();
  for (int it = 0; it < 1000; ++it) {
    if (tid == 0) flag = 0;
    __syncthreads();
    int nl = 0;
    if (in && mv) {
      nl = lab[tid];
      #pragma unroll
      for (int dy = -1; dy <= 1; ++dy)
        #pragma unroll
        for (int dx = -1; dx <= 1; ++dx) {
          int yy = y + dy, xx = x + dx;
          if ((unsigned)yy < 25u && (unsigned)xx < 25u) nl = max(nl, lab[yy * 25 + xx]);
        }
    }
    __syncthreads();
    if (in && mv && nl != lab[tid]) { lab[tid] = nl; flag = 1; }
    __syncthreads();
    if (flag == 0) break;
  }
  if (tid < 626) counts[tid] = (tid == 0) ? -1 : 0;
  if (tid == 0) best = (int)0x80000000;
  __syncthreads();
  if (in && mv) atomicAdd(&counts[lab[tid]], 1);
  __syncthreads();
  if (tid < 626) atomicMax(&best, counts[tid] * 1024 + (1023 - tid));
  __syncthreads();
  const int largest = 1023 - (best & 1023);
  const bool comp = in && mv && (lab[tid] == largest);
  const bool bg = in && !comp;
  const bool border = in && (y == 0 || y == 24 || x == 0 || x == 24);
  __syncthreads();
  if (in) lab[tid] = (bg && border) ? 1 : 0;
  __syncthreads();
  for (int it = 0; it < 1000; ++it) {
    if (tid == 0) flag = 0;
    __syncthreads();
    int r = 0;
    if (in && bg && !lab[tid]) {
      if (y > 0  && lab[tid - 25]) r = 1;
      if (y < 24 && lab[tid + 25]) r = 1;
      if (x > 0  && lab[tid - 1])  r = 1;
      if (x < 24 && lab[tid + 1])  r = 1;
    }
    __syncthreads();
    if (r) { lab[tid] = 1; flag = 1; }
    __syncthreads();
    if (flag == 0) break;
  }
  if (in) mask[(size_t)b * NX + tid] = lab[tid] ? 0.f : 1.f;
}

extern "C" void kernel_launch(void* const* d_in, const int* in_sizes, int n_in,
                              void* d_out, int out_size, void* d_ws, size_t ws_size,
                              hipStream_t stream) {
  const float* zf     = (const float*)d_in[0];
  const float* xf     = (const float*)d_in[1];
  const float* sup_w  = (const float*)d_in[2];
  const float* sup_b  = (const float*)d_in[3];
  const float* sup_g  = (const float*)d_in[4];
  const float* sup_be = (const float*)d_in[5];
  const float* sup_m  = (const float*)d_in[6];
  const float* sup_v  = (const float*)d_in[7];
  const float* q_w    = (const float*)d_in[8];
  const float* q_b    = (const float*)d_in[9];
  const float* q_g    = (const float*)d_in[10];
  const float* q_be   = (const float*)d_in[11];
  const float* q_m    = (const float*)d_in[12];
  const float* q_v    = (const float*)d_in[13];
  const float* g_w1   = (const float*)d_in[14];
  const float* g_b1   = (const float*)d_in[15];
  const float* g_w2   = (const float*)d_in[16];
  const float* g_b2   = (const float*)d_in[17];
  const float* g_g    = (const float*)d_in[18];
  const float* g_be   = (const float*)d_in[19];
  const float* g_m    = (const float*)d_in[20];
  const float* g_v    = (const float*)d_in[21];
  const float* fi_w   = (const float*)d_in[22];
  const float* fi_b   = (const float*)d_in[23];
  const float* fi_g   = (const float*)d_in[24];
  const float* fi_be  = (const float*)d_in[25];
  const float* fi_m   = (const float*)d_in[26];
  const float* fi_v   = (const float*)d_in[27];
  const float* fi1_w  = (const float*)d_in[28];
  const float* fi1_b  = (const float*)d_in[29];
  const float* fi1_g  = (const float*)d_in[30];
  const float* fi1_be = (const float*)d_in[31];
  const float* fi1_m  = (const float*)d_in[32];
  const float* fi1_v  = (const float*)d_in[33];

  float* ws = (float*)d_ws;
  float* xf_trans = ws;                     // 5,120,000 (dead after step 9 -> reused for f16 weights)
  float* zf_trans = xf_trans + 5120000;     // 1,384,448
  float* zf_s     = zf_trans + 1384448;     // 913,952
  float* zp2      = zf_s + 913952;          // 1,384,448
  float* si       = zp2 + 1384448;          // 3,380,000
  float* si2      = si + 3380000;           // 3,380,000 (contiguous after si!)
  float* maskb    = si2 + 3380000;          // 20,000
  float* tail     = maskb + 20000;

  // f16 activation buffers (fresh space)
  _Float16* xf16 = (_Float16*)tail;         // 32*625*256 = 5,120,000 f16
  _Float16* gt16 = xf16 + 5120000;          // 32*625*256
  _Float16* Ucat = gt16 + 5120000;          // 32*625*512 = 10,240,000
  _Float16* S16  = Ucat + 10240000;         // 32*625*192 = 3,840,000

  // f16 weight buffers overlay the (dead) xf_trans region
  _Float16* wt_g1  = (_Float16*)xf_trans;   // 9*256*256   = 589,824
  _Float16* wt_g2  = wt_g1 + 589824;        // 1*256*256   = 65,536
  _Float16* wt_fi  = wt_g2 + 65536;         // 1*256*192   = 49,152
  _Float16* wt_fi1 = wt_fi + 49152;         // 25*256*512  = 3,276,800  (total 1.99M f32 < 5.12M)

  dim3 blk(256);
  GP p;

  // ---- mask-decision chain (exact fp32) ----
  // 1) xf_trans = gelu(bn_q(q_w @ xf + q_b))   (4x8 micro, bit-identical)
  {
    G8 p8{};
    p8.A = q_w; p8.B = xf; p8.bias = q_b;
    p8.gamma = q_g; p8.beta = q_be; p8.mean = q_m; p8.var = q_v;
    p8.out = xf_trans; p8.M = CC; p8.N = NX; p8.K = CC;
    p8.aB = 0; p8.bB = (long)CC * NX; p8.outB = (long)CC * NX;
    gemm8_k<<<dim3(5,4,BB), blk, 0, stream>>>(p8);
  }

  // 2) zf_trans = gelu(bn_sup(sup_w @ zf + sup_b))
  p = GP{}; p.A = sup_w; p.B = zf; p.bias = sup_b;
  p.gamma = sup_g; p.beta = sup_be; p.mean = sup_m; p.var = sup_v;
  p.out = zf_trans; p.M = CC; p.N = NZ; p.K = CC;
  p.aB = 0; p.bB = (long)CC * NZ; p.outB = (long)CC * NZ;
  gemm_k<0,2><<<dim3(3,4,BB), blk, 0, stream>>>(p);

  // 5) zf_s_logits[n,m] = sum_c zf_trans[c,n] * zf_trans[c,m]
  p = GP{}; p.A = zf_trans; p.B = zf_trans;
  p.out = zf_s; p.M = NZ; p.N = NZ; p.K = CC;
  p.aB = (long)CC * NZ; p.bB = (long)CC * NZ; p.outB = (long)NZ * NZ;
  gemm_k<1,0><<<dim3(3,3,BB), blk, 0, stream>>>(p);

  // 6) zf_s = sparsemax(zf_s_logits) — wave-per-row, NE=3 (169 <= 192)
  sparsemax_w<3><<<(BB * NZ + 3) / 4, blk, 0, stream>>>(zf_s, NZ, BB * NZ);

  // 7) zp2[c,m] = zf[c,m] + sum_n zf[c,n] * zf_s[n,m]
  p = GP{}; p.A = zf; p.B = zf_s; p.resid = zf;
  p.out = zp2; p.M = CC; p.N = NZ; p.K = NZ;
  p.aB = (long)CC * NZ; p.bB = (long)NZ * NZ; p.outB = (long)CC * NZ;
  gemm_k<0,3><<<dim3(3,4,BB), blk, 0, stream>>>(p);

  // 8+9 fused) si/si2 logits share A = zp2 — 4x8 micro dual-B (bit-identical)
  {
    GP2 p2{};
    p2.A = zp2; p2.B1 = xf; p2.B2 = xf_trans;
    p2.out1 = si; p2.out2 = si2;
    p2.M = NZ; p2.N = NX; p2.K = CC;
    p2.aB = (long)CC * NZ; p2.bB = (long)CC * NX; p2.outB = (long)NZ * NX;
    gemm28_k<<<dim3(5,3,BB), blk, 0, stream>>>(p2);
  }

  // 10) sparsemax rows of length 625 — si and si2 contiguous: ONE launch, NE=10
  sparsemax_w<10><<<(2 * BB * NZ + 3) / 4, blk, 0, stream>>>(si, NX, 2 * BB * NZ);

  // 11) mask from si2
  cc_kernel<<<BB, dim3(640), 0, stream>>>(si2, maskb);

  // ---- xf_trans now dead: build f16 weights in its space ----
  wtr_k<<<(9*256*256 + 255)/256,  blk, 0, stream>>>(g_w1,  wt_g1,  256, 256, 256, 9);
  wtr_k<<<(256*256   + 255)/256,  blk, 0, stream>>>(g_w2,  wt_g2,  256, 256, 256, 1);
  wtr_k<<<(256*192   + 255)/256,  blk, 0, stream>>>(fi_w,  wt_fi,  256, 169, 192, 1);
  wtr_k<<<(25*256*512+ 255)/256,  blk, 0, stream>>>(fi1_w, wt_fi1, 256, 512, 512, 25);

  // ---- activation conversions to f16 NHWC ----
  cvt_k<<<(long)(BB*NX*256 + 255)/256, blk, 0, stream>>>(xf, nullptr, xf16, 256, 256, (long)BB*NX*256);
  cvt_k<<<(long)(BB*NX*192 + 255)/256, blk, 0, stream>>>(si, si2, S16, 169, 192, (long)BB*NX*192);

  // ---- output path on MFMA (f16 in, fp32 accum), NHWC B operands ----
  MP mp;

  // 3) gt16 = conv3x3(xf, g_w1) + g_b1   (f16 NHWC out)
  mp = MP{}; mp.Wt = wt_g1; mp.U = xf16; mp.bias = g_b1;
  mp.out16 = gt16; mp.R = 9; mp.Rw = 3; mp.C2p = 256;
  mp.uB = (long)NX * 256; mp.oC2p = 256; mp.oCoff = 0;
  mgemm_k<1,1,0><<<dim3(10,4,BB), blk, 0, stream>>>(mp);

  // 4) Ucat[:,256:512] = gelu(bn_g(g_w2 @ gt16 + g_b2))
  mp = MP{}; mp.Wt = wt_g2; mp.U = gt16; mp.bias = g_b2;
  mp.gamma = g_g; mp.beta = g_be; mp.mean = g_m; mp.var = g_v;
  mp.out16 = Ucat; mp.R = 1; mp.Rw = 1; mp.C2p = 256;
  mp.uB = (long)NX * 256; mp.oC2p = 512; mp.oCoff = 256;
  mgemm_k<2,1,0><<<dim3(10,4,BB), blk, 0, stream>>>(mp);

  // 12) Ucat[:,0:256] = gelu(bn_fi(fi_w @ (si + si2) + fi_b))
  mp = MP{}; mp.Wt = wt_fi; mp.U = S16; mp.bias = fi_b;
  mp.gamma = fi_g; mp.beta = fi_be; mp.mean = fi_m; mp.var = fi_v;
  mp.out16 = Ucat; mp.R = 1; mp.Rw = 1; mp.C2p = 192;
  mp.uB = (long)NX * 192; mp.oC2p = 512; mp.oCoff = 0;
  mgemm_k<2,1,0><<<dim3(10,4,BB), blk, 0, stream>>>(mp);

  // 13) out = gelu(bn_fi1(conv5x5(Ucat with mask on c>=256, fi1_w) + fi1_b))
  mp = MP{}; mp.Wt = wt_fi1; mp.U = Ucat; mp.mask = maskb;
  mp.bias = fi1_b; mp.gamma = fi1_g; mp.beta = fi1_be; mp.mean = fi1_m; mp.var = fi1_v;
  mp.out = (float*)d_out; mp.R = 25; mp.Rw = 5; mp.C2p = 512;
  mp.uB = (long)NX * 512;
  mgemm_k<2,0,1><<<dim3(10,4,BB), blk, 0, stream>>>(mp);
}

// Round 20
// 782.723 us; speedup vs baseline: 1.0729x; 1.0729x over previous
//
#include <hip/hip_runtime.h>
#include <hip/hip_bf16.h>
#include <math.h>

// Problem constants
#define BB  32
#define CC  256
#define NZ  169     // 13*13
#define NX  625     // 25*25

typedef _Float16 f16x4 __attribute__((ext_vector_type(4)));
typedef _Float16 f16x8 __attribute__((ext_vector_type(8)));
typedef float    f32x4 __attribute__((ext_vector_type(4)));

__device__ __forceinline__ float geluf(float x) {
  return 0.5f * x * (1.0f + erff(x * 0.7071067811865476f));
}

// ======================= fp32 vector GEMM (mask-path ops) =======================
struct GP {
  const float* A;  const float* B;
  const float* bias; const float* gamma; const float* beta; const float* mean; const float* var;
  const float* resid;
  float* out;
  int M, N, K;
  long aB, bB, outB;
};

#define TM 64
#define TN 64
#define TK 16

// AG: 0 = A[m,k] row-major ; 1 = A[m,k] = Abase[k*M + m]
// EPI:0 = none ; 2 = +bias,BN,GELU ; 3 = +resid
template<int AG, int EPI>
__global__ __launch_bounds__(256) void gemm_k(GP p) {
  const int b  = blockIdx.z;
  const int m0 = blockIdx.y * TM;
  const int n0 = blockIdx.x * TN;
  const float* Ab = p.A + (size_t)b * p.aB;
  const float* Bb = p.B + (size_t)b * p.bB;
  __shared__ __align__(16) float As[TK][TM + 4];
  __shared__ __align__(16) float Bs[TK][TN + 4];
  const int tid = threadIdx.x;
  const int tx = tid & 15, ty = tid >> 4;
  float acc[4][4] = {{0.f}};
  const int nK = (p.K + TK - 1) / TK;
  for (int kb = 0; kb < nK; ++kb) {
    const int k0 = kb * TK;
    if (AG == 0) {
      #pragma unroll
      for (int i = 0; i < 4; ++i) {
        int e = tid * 4 + i;
        int am = e >> 4, ak = e & 15;
        int gm = m0 + am, gk = k0 + ak;
        float v = 0.f;
        if (gm < p.M && gk < p.K) v = Ab[(size_t)gm * p.K + gk];
        As[ak][am] = v;
      }
    } else {
      #pragma unroll
      for (int i = 0; i < 4; ++i) {
        int e = tid + 256 * i;
        int ak = e >> 6, am = e & 63;
        int gm = m0 + am, gk = k0 + ak;
        float v = 0.f;
        if (gm < p.M && gk < p.K) v = Ab[(size_t)gk * p.M + gm];
        As[ak][am] = v;
      }
    }
    #pragma unroll
    for (int i = 0; i < 4; ++i) {
      int e = tid + 256 * i;
      int bk = e >> 6, bn = e & 63;
      int gk = k0 + bk, gn = n0 + bn;
      float v = 0.f;
      if (gk < p.K && gn < p.N) v = Bb[(size_t)gk * p.N + gn];
      Bs[bk][bn] = v;
    }
    __syncthreads();
    #pragma unroll
    for (int kk = 0; kk < TK; ++kk) {
      float av[4], bv[4];
      #pragma unroll
      for (int i2 = 0; i2 < 4; ++i2) av[i2] = As[kk][ty * 4 + i2];
      #pragma unroll
      for (int j2 = 0; j2 < 4; ++j2) bv[j2] = Bs[kk][tx * 4 + j2];
      #pragma unroll
      for (int i2 = 0; i2 < 4; ++i2)
        #pragma unroll
        for (int j2 = 0; j2 < 4; ++j2)
          acc[i2][j2] = fmaf(av[i2], bv[j2], acc[i2][j2]);
    }
    __syncthreads();
  }
  #pragma unroll
  for (int i = 0; i < 4; ++i) {
    int gm = m0 + ty * 4 + i;
    if (gm >= p.M) continue;
    float bs = 0.f, sBN = 1.f, tBN = 0.f;
    if (EPI == 2) {
      bs = p.bias[gm];
      float sc = p.gamma[gm] / sqrtf(p.var[gm] + 1e-5f);
      sBN = sc; tBN = p.beta[gm] - p.mean[gm] * sc;
    }
    #pragma unroll
    for (int j = 0; j < 4; ++j) {
      int gn = n0 + tx * 4 + j;
      if (gn >= p.N) continue;
      float v = acc[i][j];
      if (EPI == 2) { v += bs; v = v * sBN + tBN; v = geluf(v); }
      if (EPI == 3) v += p.resid[(size_t)b * p.outB + (size_t)gm * p.N + gn];
      p.out[(size_t)b * p.outB + (size_t)gm * p.N + gn] = v;
    }
  }
}

// ============ dual fp32 GEMM: shared A (transposed gather), two B's ============
// out1[n,m] = sum_c A[c,n]*B1[c,m] ; out2[n,m] = sum_c A[c,n]*B2[c,m]
struct GP2 {
  const float* A; const float* B1; const float* B2;
  float* out1; float* out2;
  int M, N, K;                 // M=169, N=625, K=256
  long aB, bB, outB;           // per-batch strides (A: C*NZ, B: C*NX, out: NZ*NX)
};

__global__ __launch_bounds__(256) void gemm2_k(GP2 p) {
  const int b  = blockIdx.z;
  const int m0 = blockIdx.y * TM;
  const int n0 = blockIdx.x * TN;
  const float* Ab  = p.A  + (size_t)b * p.aB;
  const float* B1b = p.B1 + (size_t)b * p.bB;
  const float* B2b = p.B2 + (size_t)b * p.bB;
  __shared__ __align__(16) float As [TK][TM + 4];
  __shared__ __align__(16) float Bs1[TK][TN + 4];
  __shared__ __align__(16) float Bs2[TK][TN + 4];
  const int tid = threadIdx.x;
  const int tx = tid & 15, ty = tid >> 4;
  float acc1[4][4] = {{0.f}};
  float acc2[4][4] = {{0.f}};
  const int nK = (p.K + TK - 1) / TK;
  for (int kb = 0; kb < nK; ++kb) {
    const int k0 = kb * TK;
    #pragma unroll
    for (int i = 0; i < 4; ++i) {
      int e = tid + 256 * i;
      int ak = e >> 6, am = e & 63;
      int gm = m0 + am, gk = k0 + ak;
      float v = 0.f;
      if (gm < p.M && gk < p.K) v = Ab[(size_t)gk * p.M + gm];
      As[ak][am] = v;
    }
    #pragma unroll
    for (int i = 0; i < 4; ++i) {
      int e = tid + 256 * i;
      int bk = e >> 6, bn = e & 63;
      int gk = k0 + bk, gn = n0 + bn;
      float v1 = 0.f, v2 = 0.f;
      if (gk < p.K && gn < p.N) {
        v1 = B1b[(size_t)gk * p.N + gn];
        v2 = B2b[(size_t)gk * p.N + gn];
      }
      Bs1[bk][bn] = v1;
      Bs2[bk][bn] = v2;
    }
    __syncthreads();
    #pragma unroll
    for (int kk = 0; kk < TK; ++kk) {
      float av[4], bv1[4], bv2[4];
      #pragma unroll
      for (int i2 = 0; i2 < 4; ++i2) av[i2] = As[kk][ty * 4 + i2];
      #pragma unroll
      for (int j2 = 0; j2 < 4; ++j2) { bv1[j2] = Bs1[kk][tx * 4 + j2]; bv2[j2] = Bs2[kk][tx * 4 + j2]; }
      #pragma unroll
      for (int i2 = 0; i2 < 4; ++i2)
        #pragma unroll
        for (int j2 = 0; j2 < 4; ++j2) {
          acc1[i2][j2] = fmaf(av[i2], bv1[j2], acc1[i2][j2]);
          acc2[i2][j2] = fmaf(av[i2], bv2[j2], acc2[i2][j2]);
        }
    }
    __syncthreads();
  }
  #pragma unroll
  for (int i = 0; i < 4; ++i) {
    int gm = m0 + ty * 4 + i;
    if (gm >= p.M) continue;
    #pragma unroll
    for (int j = 0; j < 4; ++j) {
      int gn = n0 + tx * 4 + j;
      if (gn >= p.N) continue;
      size_t o = (size_t)b * p.outB + (size_t)gm * p.N + gn;
      p.out1[o] = acc1[i][j];
      p.out2[o] = acc2[i][j];
    }
  }
}

// ======================= weight pre-transpose to f16 =======================
// W [M][C2][R] fp32  ->  Wt [R][M][C2p] f16 (zero-padded c >= C2)
__global__ __launch_bounds__(256) void wtr_k(const float* __restrict__ W,
                                             _Float16* __restrict__ Wt,
                                             int M, int C2, int C2p, int R) {
  size_t o = (size_t)blockIdx.x * 256 + threadIdx.x;
  size_t total = (size_t)R * M * C2p;
  if (o >= total) return;
  int c = (int)(o % C2p);
  int t = (int)(o / C2p);
  int m = t % M;
  int r = t / M;
  float v = 0.f;
  if (c < C2) v = W[((size_t)m * C2 + c) * R + r];
  Wt[o] = (_Float16)v;
}

// ======================= NCHW f32 (+opt add) -> NHWC f16 =======================
__global__ __launch_bounds__(256) void cvt_k(const float* __restrict__ A,
                                             const float* __restrict__ A2,
                                             _Float16* __restrict__ O,
                                             int C, int Cp, long total) {
  long o = (long)blockIdx.x * 256 + threadIdx.x;
  if (o >= total) return;
  int c = (int)(o % Cp);
  long t = o / Cp;
  int pp = (int)(t % NX);
  int b = (int)(t / NX);
  float v = 0.f;
  if (c < C) {
    size_t src = ((size_t)b * C + c) * NX + pp;
    v = A[src];
    if (A2) v += A2[src];
  }
  O[o] = (_Float16)v;
}

// ======================= f16 MFMA conv-as-GEMM (NHWC acts) =======================
// out[b][m][n] = epi( sum_{r,c} Wt[r][m][c] * U[b][pix(n,r)][c] )
// 64x64 tile, 4 waves (each 32x32), 16x16x32 MFMA, swizzled LDS (stride 64 f16,
// 16B-slot XOR), XCD-aware block swizzle. Grid MUST be dim3(10,4,32) = 1280.
// == R11 measured-best structure — DO NOT perturb (R13/R14/R15 all regressed) ==
struct MP {
  const _Float16* Wt;       // [R][256][C2p]
  const _Float16* U;        // [b][625][C2p]
  const float* mask;        // [b][625] (MASKED: applies to c>=256)
  const float* bias; const float* gamma; const float* beta; const float* mean; const float* var;
  float* out;               // f32 NCHW [b][256][625]   (OUT16 == 0)
  _Float16* out16;          // f16 NHWC [b][625][oC2p]  (OUT16 == 1)
  int R, Rw, C2p;
  long uB;                  // per-batch U stride
  int oC2p, oCoff;
};

// EPI: 1 = +bias ; 2 = +bias,BN,GELU
template<int EPI, int OUT16, int MASKED>
__global__ __launch_bounds__(256) void mgemm_k(MP p) {
  // ---- XCD-aware bijective swizzle: XCD x handles batches 4x..4x+3 ----
  const int L   = blockIdx.x + 10 * (blockIdx.y + 4 * blockIdx.z); // 0..1279
  const int xcd = L & 7;
  const int j   = L >> 3;                 // 0..159
  const int jb  = j / 40;                 // 0..3
  const int b   = (xcd << 2) + jb;
  const int t   = j - jb * 40;            // 0..39
  const int m0  = (t / 10) * 64;
  const int n0  = (t - (t / 10) * 10) * 64;

  __shared__ __align__(16) _Float16 As[64][64];   // 128B rows, swizzled 16B slots
  __shared__ __align__(16) _Float16 Bs[64][64];
  const int tid = threadIdx.x;
  const int w = tid >> 6, lane = tid & 63;
  const int wm = w & 1, wn = w >> 1;                // wave -> 32x32 sub-tile
  const int lm = lane & 15, q = lane >> 4;          // q = k-group 0..3
  const int sr = tid >> 2, sc4 = tid & 3;           // stage: row/pixel, 16-chan chunk
  const int scc = sc4 * 16;
  const int sr7 = sr & 7, sb = sc4 * 2;
  const int ng = n0 + sr;
  const bool nv = ng < NX;
  const int py = ng / 25, px = ng - (ng / 25) * 25;
  const _Float16* Ub = p.U + (size_t)b * p.uB;
  const float* mb = MASKED ? (p.mask + (size_t)b * NX) : nullptr;
  const int pad = p.Rw >> 1;

  f32x4 acc[2][2] = {};

  for (int r = 0; r < p.R; ++r) {
    const int kh = r / p.Rw, kw = r - (r / p.Rw) * p.Rw;
    const int iy = py + kh - pad, ix = px + kw - pad;
    const bool pv = nv && ((unsigned)iy < 25u) && ((unsigned)ix < 25u);
    const int pp = iy * 25 + ix;
    const _Float16* Up = pv ? (Ub + (size_t)pp * p.C2p) : nullptr;
    _Float16 mh = (_Float16)1.f;
    if (MASKED && pv) mh = (_Float16)mb[pp];
    const _Float16* Wr = p.Wt + ((size_t)r * 256 + m0) * p.C2p;
    for (int c0 = 0; c0 < p.C2p; c0 += 64) {
      // ---- A: 64x64 f16, 32 B/thread, coalesced ----
      const _Float16* Arow = Wr + (size_t)sr * p.C2p + c0 + scc;
      f16x8 a0 = *(const f16x8*)(Arow);
      f16x8 a1 = *(const f16x8*)(Arow + 8);
      // ---- B: 64x64 f16, 32 B/thread, coalesced ----
      f16x8 v0 = {}, v1 = {};
      if (pv) {
        const _Float16* Bp = Up + c0 + scc;
        v0 = *(const f16x8*)(Bp);
        v1 = *(const f16x8*)(Bp + 8);
        if (MASKED && (c0 + scc) >= 256) { v0 = v0 * mh; v1 = v1 * mh; }
      }
      *(f16x8*)&As[sr][((sb + 0) ^ sr7) << 3] = a0;
      *(f16x8*)&As[sr][((sb + 1) ^ sr7) << 3] = a1;
      *(f16x8*)&Bs[sr][((sb + 0) ^ sr7) << 3] = v0;
      *(f16x8*)&Bs[sr][((sb + 1) ^ sr7) << 3] = v1;
      __syncthreads();
      // ---- MFMA 16x16x32: wave (wm,wn) -> rows wm*32+ , cols wn*32+ ----
      #pragma unroll
      for (int ks = 0; ks < 2; ++ks) {
        const int so = (((ks << 2) + q) ^ (lm & 7)) << 3;  // rows ≡ lm (mod 8)
        f16x8 af[2], bf[2];
        #pragma unroll
        for (int fm = 0; fm < 2; ++fm)
          af[fm] = *(const f16x8*)&As[wm * 32 + fm * 16 + lm][so];
        #pragma unroll
        for (int fn = 0; fn < 2; ++fn)
          bf[fn] = *(const f16x8*)&Bs[wn * 32 + fn * 16 + lm][so];
        #pragma unroll
        for (int fm = 0; fm < 2; ++fm)
          #pragma unroll
          for (int fn = 0; fn < 2; ++fn)
            acc[fm][fn] = __builtin_amdgcn_mfma_f32_16x16x32_f16(
                af[fm], bf[fn], acc[fm][fn], 0, 0, 0);
      }
      __syncthreads();
    }
  }
  // ---- epilogue (C/D layout: col=lane&15, row=(lane>>4)*4+reg) ----
  #pragma unroll
  for (int fm = 0; fm < 2; ++fm) {
    const int rbase = m0 + wm * 32 + fm * 16 + q * 4;
    #pragma unroll
    for (int rr = 0; rr < 4; ++rr) {
      const int row = rbase + rr;
      float bs = p.bias[row];
      float sBN = 1.f, tBN = 0.f;
      if (EPI == 2) {
        float sc = p.gamma[row] / sqrtf(p.var[row] + 1e-5f);
        sBN = sc; tBN = p.beta[row] - p.mean[row] * sc;
      }
      #pragma unroll
      for (int fn = 0; fn < 2; ++fn) {
        const int col = n0 + wn * 32 + fn * 16 + lm;
        if (col < NX) {
          float v = acc[fm][fn][rr] + bs;
          if (EPI == 2) v = geluf(v * sBN + tBN);
          if (OUT16) {
            p.out16[((size_t)b * NX + col) * p.oC2p + p.oCoff + row] = (_Float16)v;
          } else {
            p.out[(size_t)b * (256 * NX) + (size_t)row * NX + col] = v;
          }
        }
      }
    }
  }
}

// ---------------- sparsemax (exact, Michelot projection) ----------------
// WAVE-per-row: lane holds NE strided elements; shfl-tree reductions only,
// zero barriers, zero LDS. 4 rows per 256-thread block.
template<int NE>
__global__ __launch_bounds__(256) void sparsemax_w(float* __restrict__ S,
                                                   int d, int nrows) {
  const int row = blockIdx.x * 4 + (threadIdx.x >> 6);
  const int lane = threadIdx.x & 63;
  if (row >= nrows) return;
  float* s = S + (size_t)row * d;
  float v[NE]; bool act[NE];
  #pragma unroll
  for (int j = 0; j < NE; ++j) {
    int idx = lane + 64 * j;
    bool ok = idx < d;
    act[j] = ok;
    v[j] = ok ? s[idx] : -1e30f;
  }
  // row max (wave shfl tree)
  float mx = v[0];
  #pragma unroll
  for (int j = 1; j < NE; ++j) mx = fmaxf(mx, v[j]);
  #pragma unroll
  for (int o = 32; o; o >>= 1) mx = fmaxf(mx, __shfl_down(mx, o));
  mx = __shfl(mx, 0);
  #pragma unroll
  for (int j = 0; j < NE; ++j) if (act[j]) v[j] -= mx;
  float tau = 0.f;
  for (int it = 0; it < 700; ++it) {
    float ls = 0.f, lc = 0.f;
    #pragma unroll
    for (int j = 0; j < NE; ++j) if (act[j]) { ls += v[j]; lc += 1.f; }
    #pragma unroll
    for (int o = 32; o; o >>= 1) { ls += __shfl_down(ls, o); lc += __shfl_down(lc, o); }
    ls = __shfl(ls, 0); lc = __shfl(lc, 0);
    tau = (ls - 1.f) / lc;
    bool ch = false;
    #pragma unroll
    for (int j = 0; j < NE; ++j)
      if (act[j] && v[j] <= tau) { act[j] = false; ch = true; }
    if (!__any(ch)) break;
  }
  #pragma unroll
  for (int j = 0; j < NE; ++j) {
    int idx = lane + 64 * j;
    if (idx < d) s[idx] = fmaxf(v[j] - tau, 0.f);
  }
}

// ------------- mask: any(si2>0) -> largest 8-CC -> fill holes -------------
__global__ __launch_bounds__(640) void cc_kernel(const float* __restrict__ si2,
                                                 float* __restrict__ mask) {
  const int b = blockIdx.x, tid = threadIdx.x;
  __shared__ int lab[625];
  __shared__ int counts[626];
  __shared__ int flag, best;
  const bool in = tid < 625;
  const int y = tid / 25, x = tid - (tid / 25) * 25;
  bool mv = false;
  if (in) {
    const float* base = si2 + (size_t)b * NZ * NX + tid;
    for (int n = 0; n < NZ; ++n) mv = mv || (base[(size_t)n * NX] > 0.f);
    lab[tid] = mv ? tid + 1 : 0;
  }
  __syncthreads();
  for (int it = 0; it < 1000; ++it) {
    if (tid == 0) flag = 0;
    __syncthreads();
    int nl = 0;
    if (in && mv) {
      nl = lab[tid];
      #pragma unroll
      for (int dy = -1; dy <= 1; ++dy)
        #pragma unroll
        for (int dx = -1; dx <= 1; ++dx) {
          int yy = y + dy, xx = x + dx;
          if ((unsigned)yy < 25u && (unsigned)xx < 25u) nl = max(nl, lab[yy * 25 + xx]);
        }
    }
    __syncthreads();
    if (in && mv && nl != lab[tid]) { lab[tid] = nl; flag = 1; }
    __syncthreads();
    if (flag == 0) break;
  }
  if (tid < 626) counts[tid] = (tid == 0) ? -1 : 0;
  if (tid == 0) best = (int)0x80000000;
  __syncthreads();
  if (in && mv) atomicAdd(&counts[lab[tid]], 1);
  __syncthreads();
  if (tid < 626) atomicMax(&best, counts[tid] * 1024 + (1023 - tid));
  __syncthreads();
  const int largest = 1023 - (best & 1023);
  const bool comp = in && mv && (lab[tid] == largest);
  const bool bg = in && !comp;
  const bool border = in && (y == 0 || y == 24 || x == 0 || x == 24);
  __syncthreads();
  if (in) lab[tid] = (bg && border) ? 1 : 0;
  __syncthreads();
  for (int it = 0; it < 1000; ++it) {
    if (tid == 0) flag = 0;
    __syncthreads();
    int r = 0;
    if (in && bg && !lab[tid]) {
      if (y > 0  && lab[tid - 25]) r = 1;
      if (y < 24 && lab[tid + 25]) r = 1;
      if (x > 0  && lab[tid - 1])  r = 1;
      if (x < 24 && lab[tid + 1])  r = 1;
    }
    __syncthreads();
    if (r) { lab[tid] = 1; flag = 1; }
    __syncthreads();
    if (flag == 0) break;
  }
  if (in) mask[(size_t)b * NX + tid] = lab[tid] ? 0.f : 1.f;
}

extern "C" void kernel_launch(void* const* d_in, const int* in_sizes, int n_in,
                              void* d_out, int out_size, void* d_ws, size_t ws_size,
                              hipStream_t stream) {
  const float* zf     = (const float*)d_in[0];
  const float* xf     = (const float*)d_in[1];
  const float* sup_w  = (const float*)d_in[2];
  const float* sup_b  = (const float*)d_in[3];
  const float* sup_g  = (const float*)d_in[4];
  const float* sup_be = (const float*)d_in[5];
  const float* sup_m  = (const float*)d_in[6];
  const float* sup_v  = (const float*)d_in[7];
  const float* q_w    = (const float*)d_in[8];
  const float* q_b    = (const float*)d_in[9];
  const float* q_g    = (const float*)d_in[10];
  const float* q_be   = (const float*)d_in[11];
  const float* q_m    = (const float*)d_in[12];
  const float* q_v    = (const float*)d_in[13];
  const float* g_w1   = (const float*)d_in[14];
  const float* g_b1   = (const float*)d_in[15];
  const float* g_w2   = (const float*)d_in[16];
  const float* g_b2   = (const float*)d_in[17];
  const float* g_g    = (const float*)d_in[18];
  const float* g_be   = (const float*)d_in[19];
  const float* g_m    = (const float*)d_in[20];
  const float* g_v    = (const float*)d_in[21];
  const float* fi_w   = (const float*)d_in[22];
  const float* fi_b   = (const float*)d_in[23];
  const float* fi_g   = (const float*)d_in[24];
  const float* fi_be  = (const float*)d_in[25];
  const float* fi_m   = (const float*)d_in[26];
  const float* fi_v   = (const float*)d_in[27];
  const float* fi1_w  = (const float*)d_in[28];
  const float* fi1_b  = (const float*)d_in[29];
  const float* fi1_g  = (const float*)d_in[30];
  const float* fi1_be = (const float*)d_in[31];
  const float* fi1_m  = (const float*)d_in[32];
  const float* fi1_v  = (const float*)d_in[33];

  float* ws = (float*)d_ws;
  float* xf_trans = ws;                     // 5,120,000 (dead after step 9 -> reused for f16 weights)
  float* zf_trans = xf_trans + 5120000;     // 1,384,448
  float* zf_s     = zf_trans + 1384448;     // 913,952
  float* zp2      = zf_s + 913952;          // 1,384,448
  float* si       = zp2 + 1384448;          // 3,380,000
  float* si2      = si + 3380000;           // 3,380,000 (contiguous after si!)
  float* maskb    = si2 + 3380000;          // 20,000
  float* tail     = maskb + 20000;

  // f16 activation buffers (fresh space)
  _Float16* xf16 = (_Float16*)tail;         // 32*625*256 = 5,120,000 f16
  _Float16* gt16 = xf16 + 5120000;          // 32*625*256
  _Float16* Ucat = gt16 + 5120000;          // 32*625*512 = 10,240,000
  _Float16* S16  = Ucat + 10240000;         // 32*625*192 = 3,840,000

  // f16 weight buffers overlay the (dead) xf_trans region
  _Float16* wt_g1  = (_Float16*)xf_trans;   // 9*256*256   = 589,824
  _Float16* wt_g2  = wt_g1 + 589824;        // 1*256*256   = 65,536
  _Float16* wt_fi  = wt_g2 + 65536;         // 1*256*192   = 49,152
  _Float16* wt_fi1 = wt_fi + 49152;         // 25*256*512  = 3,276,800  (total 1.99M f32 < 5.12M)

  dim3 blk(256);
  GP p;

  // ---- mask-decision chain (exact fp32) ----
  // 1) xf_trans = gelu(bn_q(q_w @ xf + q_b))
  p = GP{}; p.A = q_w; p.B = xf; p.bias = q_b;
  p.gamma = q_g; p.beta = q_be; p.mean = q_m; p.var = q_v;
  p.out = xf_trans; p.M = CC; p.N = NX; p.K = CC;
  p.aB = 0; p.bB = (long)CC * NX; p.outB = (long)CC * NX;
  gemm_k<0,2><<<dim3(10,4,BB), blk, 0, stream>>>(p);

  // 2) zf_trans = gelu(bn_sup(sup_w @ zf + sup_b))
  p = GP{}; p.A = sup_w; p.B = zf; p.bias = sup_b;
  p.gamma = sup_g; p.beta = sup_be; p.mean = sup_m; p.var = sup_v;
  p.out = zf_trans; p.M = CC; p.N = NZ; p.K = CC;
  p.aB = 0; p.bB = (long)CC * NZ; p.outB = (long)CC * NZ;
  gemm_k<0,2><<<dim3(3,4,BB), blk, 0, stream>>>(p);

  // 5) zf_s_logits[n,m] = sum_c zf_trans[c,n] * zf_trans[c,m]
  p = GP{}; p.A = zf_trans; p.B = zf_trans;
  p.out = zf_s; p.M = NZ; p.N = NZ; p.K = CC;
  p.aB = (long)CC * NZ; p.bB = (long)CC * NZ; p.outB = (long)NZ * NZ;
  gemm_k<1,0><<<dim3(3,3,BB), blk, 0, stream>>>(p);

  // 6) zf_s = sparsemax(zf_s_logits) — wave-per-row, NE=3 (169 <= 192)
  sparsemax_w<3><<<(BB * NZ + 3) / 4, blk, 0, stream>>>(zf_s, NZ, BB * NZ);

  // 7) zp2[c,m] = zf[c,m] + sum_n zf[c,n] * zf_s[n,m]
  p = GP{}; p.A = zf; p.B = zf_s; p.resid = zf;
  p.out = zp2; p.M = CC; p.N = NZ; p.K = NZ;
  p.aB = (long)CC * NZ; p.bB = (long)NZ * NZ; p.outB = (long)CC * NZ;
  gemm_k<0,3><<<dim3(3,4,BB), blk, 0, stream>>>(p);

  // 8+9 fused) si/si2 logits share A = zp2 — stage A once, two B's
  {
    GP2 p2{};
    p2.A = zp2; p2.B1 = xf; p2.B2 = xf_trans;
    p2.out1 = si; p2.out2 = si2;
    p2.M = NZ; p2.N = NX; p2.K = CC;
    p2.aB = (long)CC * NZ; p2.bB = (long)CC * NX; p2.outB = (long)NZ * NX;
    gemm2_k<<<dim3(10,3,BB), blk, 0, stream>>>(p2);
  }

  // 10) sparsemax rows of length 625 — si and si2 contiguous: ONE launch, NE=10
  sparsemax_w<10><<<(2 * BB * NZ + 3) / 4, blk, 0, stream>>>(si, NX, 2 * BB * NZ);

  // 11) mask from si2
  cc_kernel<<<BB, dim3(640), 0, stream>>>(si2, maskb);

  // ---- xf_trans now dead: build f16 weights in its space ----
  wtr_k<<<(9*256*256 + 255)/256,  blk, 0, stream>>>(g_w1,  wt_g1,  256, 256, 256, 9);
  wtr_k<<<(256*256   + 255)/256,  blk, 0, stream>>>(g_w2,  wt_g2,  256, 256, 256, 1);
  wtr_k<<<(256*192   + 255)/256,  blk, 0, stream>>>(fi_w,  wt_fi,  256, 169, 192, 1);
  wtr_k<<<(25*256*512+ 255)/256,  blk, 0, stream>>>(fi1_w, wt_fi1, 256, 512, 512, 25);

  // ---- activation conversions to f16 NHWC ----
  cvt_k<<<(long)(BB*NX*256 + 255)/256, blk, 0, stream>>>(xf, nullptr, xf16, 256, 256, (long)BB*NX*256);
  cvt_k<<<(long)(BB*NX*192 + 255)/256, blk, 0, stream>>>(si, si2, S16, 169, 192, (long)BB*NX*192);

  // ---- output path on MFMA (f16 in, fp32 accum), NHWC B operands ----
  MP mp;

  // 3) gt16 = conv3x3(xf, g_w1) + g_b1   (f16 NHWC out)
  mp = MP{}; mp.Wt = wt_g1; mp.U = xf16; mp.bias = g_b1;
  mp.out16 = gt16; mp.R = 9; mp.Rw = 3; mp.C2p = 256;
  mp.uB = (long)NX * 256; mp.oC2p = 256; mp.oCoff = 0;
  mgemm_k<1,1,0><<<dim3(10,4,BB), blk, 0, stream>>>(mp);

  // 4) Ucat[:,256:512] = gelu(bn_g(g_w2 @ gt16 + g_b2))
  mp = MP{}; mp.Wt = wt_g2; mp.U = gt16; mp.bias = g_b2;
  mp.gamma = g_g; mp.beta = g_be; mp.mean = g_m; mp.var = g_v;
  mp.out16 = Ucat; mp.R = 1; mp.Rw = 1; mp.C2p = 256;
  mp.uB = (long)NX * 256; mp.oC2p = 512; mp.oCoff = 256;
  mgemm_k<2,1,0><<<dim3(10,4,BB), blk, 0, stream>>>(mp);

  // 12) Ucat[:,0:256] = gelu(bn_fi(fi_w @ (si + si2) + fi_b))
  mp = MP{}; mp.Wt = wt_fi; mp.U = S16; mp.bias = fi_b;
  mp.gamma = fi_g; mp.beta = fi_be; mp.mean = fi_m; mp.var = fi_v;
  mp.out16 = Ucat; mp.R = 1; mp.Rw = 1; mp.C2p = 192;
  mp.uB = (long)NX * 192; mp.oC2p = 512; mp.oCoff = 0;
  mgemm_k<2,1,0><<<dim3(10,4,BB), blk, 0, stream>>>(mp);

  // 13) out = gelu(bn_fi1(conv5x5(Ucat with mask on c>=256, fi1_w) + fi1_b))
  mp = MP{}; mp.Wt = wt_fi1; mp.U = Ucat; mp.mask = maskb;
  mp.bias = fi1_b; mp.gamma = fi1_g; mp.beta = fi1_be; mp.mean = fi1_m; mp.var = fi1_v;
  mp.out = (float*)d_out; mp.R = 25; mp.Rw = 5; mp.C2p = 512;
  mp.uB = (long)NX * 512;
  mgemm_k<2,0,1><<<dim3(10,4,BB), blk, 0, stream>>>(mp);
}